// Round 9
// baseline (301.135 us; speedup 1.0000x reference)
//
#include <hip/hip_runtime.h>
#include <hip/hip_bf16.h>
#include <math.h>

#define S_LEN 4096
#define EMB   1024
#define E3    3072
#define NH    16
#define HD    64

typedef unsigned short u16;
typedef short          bfrag __attribute__((ext_vector_type(8)));  // 8 bf16
typedef float          ffrag __attribute__((ext_vector_type(4)));  // 4 f32
typedef unsigned short us8   __attribute__((ext_vector_type(8)));
typedef unsigned short us4   __attribute__((ext_vector_type(4)));

__device__ __forceinline__ u16 f2bf(float f) {
    union { float f; unsigned u; } v; v.f = f;
    unsigned r = v.u + 0x7fffu + ((v.u >> 16) & 1u);
    return (u16)(r >> 16);
}
// pack two f32 -> two bf16 (truncation) in one v_perm_b32
__device__ __forceinline__ unsigned pack_bf16_trunc(float lo, float hi) {
    union { float f; unsigned u; } a, b; a.f = lo; b.f = hi;
    return __builtin_amdgcn_perm(b.u, a.u, 0x07060302u);
}
// async global->LDS, 16B per lane; LDS dest = uniform base + lane*16
__device__ __forceinline__ void gld16(const void* g, void* l) {
    __builtin_amdgcn_global_load_lds(
        (const __attribute__((address_space(1))) unsigned int*)g,
        (__attribute__((address_space(3))) unsigned int*)l, 16, 0, 0);
}

// ---------------------------------------------------------------------------
// cast fp32 -> bf16, 8 elems/thread
// ---------------------------------------------------------------------------
__global__ __launch_bounds__(256)
void cast_bf16_kernel(const float* __restrict__ in, u16* __restrict__ out) {
    const size_t i = ((size_t)blockIdx.x * 256 + threadIdx.x) * 8;
    float4 a = *(const float4*)(in + i);
    float4 b = *(const float4*)(in + i + 4);
    us8 o;
    o[0]=f2bf(a.x); o[1]=f2bf(a.y); o[2]=f2bf(a.z); o[3]=f2bf(a.w);
    o[4]=f2bf(b.x); o[5]=f2bf(b.y); o[6]=f2bf(b.z); o[7]=f2bf(b.w);
    *(us8*)(out + i) = o;
}

// ---------------------------------------------------------------------------
// transpose+cast: in [R][C] fp32 -> out [C][R] bf16.  64x64 tiles.
// ---------------------------------------------------------------------------
__global__ __launch_bounds__(256)
void transpose_cast_kernel(const float* __restrict__ in, u16* __restrict__ out,
                           int R, int C) {
    __shared__ u16 T[64][72];
    const int r0 = blockIdx.x * 64, c0 = blockIdx.y * 64;
    const int t = threadIdx.x;
    const int rr = t >> 2, cc = (t & 3) * 16;

    const float* ip = in + (size_t)(r0 + rr) * C + c0 + cc;
    u16 tmp[16];
    #pragma unroll
    for (int i4 = 0; i4 < 4; i4++) {
        float4 v = ((const float4*)ip)[i4];
        tmp[4*i4+0]=f2bf(v.x); tmp[4*i4+1]=f2bf(v.y);
        tmp[4*i4+2]=f2bf(v.z); tmp[4*i4+3]=f2bf(v.w);
    }
    #pragma unroll
    for (int i8 = 0; i8 < 2; i8++) {
        us8 vv;
        #pragma unroll
        for (int j = 0; j < 8; j++) vv[j] = tmp[8*i8+j];
        *(us8*)&T[rr][cc + 8*i8] = vv;
    }
    __syncthreads();

    const int oc = t >> 2, orr = (t & 3) * 16;
    u16 ot[16];
    #pragma unroll
    for (int j = 0; j < 16; j++) ot[j] = T[orr + j][oc];
    u16* op = out + (size_t)(c0 + oc) * R + r0 + orr;
    #pragma unroll
    for (int i8 = 0; i8 < 2; i8++) {
        us8 vv;
        #pragma unroll
        for (int j = 0; j < 8; j++) vv[j] = ot[8*i8+j];
        *(us8*)(op + 8*i8) = vv;
    }
}

// ---------------------------------------------------------------------------
// bf16 MFMA GEMM, double-buffered: C[M,N] = A[M,K] * Bt[N,K]^T + bias
// Tile 128 x (32*NT); 4 waves as 2m x 2n; wave does 4x NT 16x16x32 tiles.
// ROPE=1 (requires NT=4):
//   n0 <  2048 : fuse RoPE rotation (+0.125*log2e scale for q) -> Cv (qkvb)
//   n0 >= 2048 : V region -- write bias-added values TRANSPOSED to vtp[d][s]
// ---------------------------------------------------------------------------
template <int OUT_BF16, int NT, int ROPE, int MINW>
__global__ __launch_bounds__(256, MINW)
void gemm_bt_kernel(const u16* __restrict__ A, const u16* __restrict__ Bt,
                    const float* __restrict__ bias, void* __restrict__ Cv,
                    u16* __restrict__ vtp, int M, int N, int K) {
    constexpr int BN = 32 * NT;       // block n-span
    constexpr int WS = 16 * NT;       // wave n-span
    __shared__ u16 As[2][128][32];
    __shared__ u16 Bs[2][BN][32];

    const int tid = threadIdx.x;
    const int w = tid >> 6, L = tid & 63;
    const int col = L & 15, quad = L >> 4;
    const int wm = w & 1, wn = w >> 1;
    const int m0 = blockIdx.x * 128, n0 = blockIdx.y * BN;

    ffrag acc[4][NT];
    #pragma unroll
    for (int a = 0; a < 4; a++)
        #pragma unroll
        for (int b = 0; b < NT; b++)
            #pragma unroll
            for (int r = 0; r < 4; r++) acc[a][b][r] = 0.f;

    const int srow = L >> 2;
    const int schk = L & 3;

    // prologue: stage k=0 into buf 0
    #pragma unroll
    for (int t = 0; t < 2; t++) {
        const int rg = (2 * w + t) * 16;
        gld16(A + (size_t)(m0 + rg + srow) * K + schk * 8, &As[0][rg][0]);
    }
    #pragma unroll
    for (int t = 0; t < NT / 2; t++) {
        const int rg = (w * (NT / 2) + t) * 16;
        gld16(Bt + (size_t)(n0 + rg + srow) * K + schk * 8, &Bs[0][rg][0]);
    }
    __syncthreads();

    int buf = 0;
    for (int k0 = 0; k0 < K; k0 += 32, buf ^= 1) {
        if (k0 + 32 < K) {
            #pragma unroll
            for (int t = 0; t < 2; t++) {
                const int rg = (2 * w + t) * 16;
                gld16(A + (size_t)(m0 + rg + srow) * K + k0 + 32 + schk * 8,
                      &As[buf ^ 1][rg][0]);
            }
            #pragma unroll
            for (int t = 0; t < NT / 2; t++) {
                const int rg = (w * (NT / 2) + t) * 16;
                gld16(Bt + (size_t)(n0 + rg + srow) * K + k0 + 32 + schk * 8,
                      &Bs[buf ^ 1][rg][0]);
            }
        }

        bfrag af[4], bf[NT];
        #pragma unroll
        for (int mt = 0; mt < 4; mt++)
            af[mt] = *(const bfrag*)&As[buf][64 * wm + 16 * mt + col][8 * quad];
        #pragma unroll
        for (int nt = 0; nt < NT; nt++)
            bf[nt] = *(const bfrag*)&Bs[buf][WS * wn + 16 * nt + col][8 * quad];
        #pragma unroll
        for (int mt = 0; mt < 4; mt++)
            #pragma unroll
            for (int nt = 0; nt < NT; nt++)
                acc[mt][nt] = __builtin_amdgcn_mfma_f32_16x16x32_bf16(
                    af[mt], bf[nt], acc[mt][nt], 0, 0, 0);

        __syncthreads();
    }

    float bv[NT];
    #pragma unroll
    for (int nt = 0; nt < NT; nt++) bv[nt] = bias[n0 + WS * wn + 16 * nt + col];

    if (ROPE && n0 < 2 * EMB) {
        // q (n<1024) or k (1024..2047): rotate (d, d+32) pairs.
        const float SCq = (n0 < EMB) ? 0.125f * 1.44269504088896f : 1.0f;
        const float C = 13.287712379549449f / 32.0f;   // log2(10000)/32
        float invf[2];
        invf[0] = exp2f(-(float)col * C);
        invf[1] = exp2f(-(float)(col + 16) * C);
        #pragma unroll
        for (int mt = 0; mt < 4; mt++) {
            #pragma unroll
            for (int r = 0; r < 4; r++) {
                const int mrow = m0 + 64 * wm + 16 * mt + 4 * quad + r;
                const float fs = (float)mrow;
                u16* cp = (u16*)Cv + (size_t)mrow * N + n0 + 64 * wn + col;
                #pragma unroll
                for (int pr = 0; pr < 2; pr++) {
                    float sn, cs;
                    sincosf(fs * invf[pr], &sn, &cs);
                    const float t1 = acc[mt][pr][r] + bv[pr];
                    const float t2 = acc[mt][pr + 2][r] + bv[pr + 2];
                    cp[16 * pr]      = f2bf((t1 * cs - t2 * sn) * SCq);
                    cp[16 * pr + 32] = f2bf((t2 * cs + t1 * sn) * SCq);
                }
            }
        }
    } else if (ROPE) {
        // V region: write transposed to vtp[d][s], d = n - 2048.
        #pragma unroll
        for (int nt = 0; nt < NT; nt++) {
            const int dg = n0 - 2 * EMB + WS * wn + 16 * nt + col;
            #pragma unroll
            for (int mt = 0; mt < 4; mt++) {
                const int s0 = m0 + 64 * wm + 16 * mt + 4 * quad;
                us4 pk;
                #pragma unroll
                for (int r = 0; r < 4; r++) pk[r] = f2bf(acc[mt][nt][r] + bv[nt]);
                *(us4*)&vtp[(size_t)dg * S_LEN + s0] = pk;
            }
        }
    } else {
        #pragma unroll
        for (int mt = 0; mt < 4; mt++) {
            #pragma unroll
            for (int r = 0; r < 4; r++) {
                const int m = m0 + 64 * wm + 16 * mt + 4 * quad + r;
                #pragma unroll
                for (int nt = 0; nt < NT; nt++) {
                    const int n = n0 + WS * wn + 16 * nt + col;
                    const float val = acc[mt][nt][r] + bv[nt];
                    if (OUT_BF16) ((u16*)Cv)[(size_t)m * N + n] = f2bf(val);
                    else          ((float*)Cv)[(size_t)m * N + n] = val;
                }
            }
        }
    }
}

// ---------------------------------------------------------------------------
// flash8: barrier-free flash.  Block = 2 waves sharing 32 q rows; each wave
// takes 32 of each 64-key tile's keys (partial O/l sums add exactly under
// static-shift softmax).  K/V/Q MFMA fragments are 16B-contiguous in global
// memory (qkvb [s][d], vt [d][s]) -> loaded DIRECTLY (L1/L2), no staging,
// no K/V LDS, no per-tile barriers.  Only P round-trips through per-wave
// LDS (lgkmcnt-ordered).  One __syncthreads at the end for the combine.
// 2048 blocks x 128 thr = 4096 waves = 4 waves/SIMD (TLP hides the serial
// QK->exp->P->PV chain).  Round-pair-balanced qi schedule; h=id&15 keeps
// 2 heads per XCD (id&7 = XCD) for L2 locality.
// ---------------------------------------------------------------------------
__global__ __launch_bounds__(128, 4)
void flash8_kernel(const u16* __restrict__ qkvb, const u16* __restrict__ vt,
                   u16* __restrict__ ctxb) {
    __shared__ u16 Ps[2][32][32];     // per-wave P tile (16B-chunk XOR swizzle)
    __shared__ float comb[34 * 64];   // wave1 partial O/l for the combine

    const int id = blockIdx.x;               // 0..2047
    const int h  = id & 15;                  // XCD = id&7 -> heads {x, x+8}
    const int qq = id >> 4;                  // 0..127
    const int rr = qq >> 4, aa = qq & 15;
    const int qi = (rr & 1) ? ((rr >> 1) * 32 + 31 - aa) : ((rr >> 1) * 32 + aa);
    const int q0 = qi * 32;
    const int ntk = qi / 2 + 1;              // 64-key tiles covering 0..q0+31

    const int tid = threadIdx.x;
    const int w = tid >> 6, L = tid & 63;
    const int col = L & 15, quad = L >> 4;

    // wave1's half of an even-qi diagonal tile is fully masked -> skip it
    int nwt = ntk;
    if (((qi & 1) == 0) && w == 1) nwt--;

    // ---- Q fragments direct from global ----
    bfrag qf[2][2];
    #pragma unroll
    for (int i = 0; i < 2; i++)
        #pragma unroll
        for (int ks = 0; ks < 2; ks++)
            qf[i][ks] = *(const bfrag*)
                (qkvb + (size_t)(q0 + 16 * i + col) * E3 + h * HD + 32 * ks + 8 * quad);

    bfrag ones;
    #pragma unroll
    for (int i = 0; i < 8; i++) ones[i] = (short)0x3F80;

    ffrag o[4][2], ol[2];
    #pragma unroll
    for (int d4 = 0; d4 < 4; d4++)
        #pragma unroll
        for (int i = 0; i < 2; i++)
            #pragma unroll
            for (int r = 0; r < 4; r++) o[d4][i][r] = 0.f;
    #pragma unroll
    for (int i = 0; i < 2; i++)
        #pragma unroll
        for (int r = 0; r < 4; r++) ol[i][r] = 0.f;

    // per-lane base pointers (advance by 64 keys per tile)
    const u16* kp0 = qkvb + (size_t)(32 * w + col) * E3 + EMB + h * HD + 8 * quad;
    const u16* kp1 = kp0 + (size_t)16 * E3;
    const u16* vp  = vt + ((size_t)h * HD + col) * S_LEN + 32 * w + 8 * quad;

    // P LDS addressing (row = q 0..31, 4x16B chunks/row, XOR swizzle)
    char* const prow_base = (char*)&Ps[w][0][0];

    #pragma unroll 1
    for (int t = 0; t < nwt; t++) {
        const size_t koff = (size_t)t * 64 * E3;
        const int    voff = t * 64;

        // ---- load K fragments (A: m=key, k=dim) and V fragments (A: m=d,
        //      k=key) directly from global ----
        bfrag kf[2][2];   // [t4l][ks]
        #pragma unroll
        for (int ks = 0; ks < 2; ks++) {
            kf[0][ks] = *(const bfrag*)(kp0 + koff + 32 * ks);
            kf[1][ks] = *(const bfrag*)(kp1 + koff + 32 * ks);
        }
        bfrag vf[4];      // [d4]
        #pragma unroll
        for (int d4 = 0; d4 < 4; d4++)
            vf[d4] = *(const bfrag*)(vp + (size_t)(16 * d4) * S_LEN + voff);

        // ---- S^T = K Q^T  (32 keys x 32 q) ----
        ffrag st[2][2];
        #pragma unroll
        for (int t4 = 0; t4 < 2; t4++)
            #pragma unroll
            for (int i = 0; i < 2; i++)
                #pragma unroll
                for (int r = 0; r < 4; r++) st[t4][i][r] = 0.f;
        #pragma unroll
        for (int ks = 0; ks < 2; ks++)
            #pragma unroll
            for (int t4 = 0; t4 < 2; t4++)
                #pragma unroll
                for (int i = 0; i < 2; i++)
                    st[t4][i] = __builtin_amdgcn_mfma_f32_16x16x32_bf16(
                        kf[t4][ks], qf[i][ks], st[t4][i], 0, 0, 0);

        // ---- causal mask: only the diagonal tile ----
        if (t == ntk - 1) {
            const int kb = 64 * t + 32 * w;      // this wave's key base
            #pragma unroll
            for (int i = 0; i < 2; i++) {
                const int qrel = q0 + 16 * i + col - kb;
                #pragma unroll
                for (int t4 = 0; t4 < 2; t4++) {
                    const int key0 = 16 * t4 + 4 * quad;
                    #pragma unroll
                    for (int r = 0; r < 4; r++)
                        if (key0 + r > qrel) st[t4][i][r] = -3.0e38f;
                }
            }
        }

        // ---- softmax numerator p = exp2(s); pack to P LDS ----
        #pragma unroll
        for (int i = 0; i < 2; i++) {
            char* const pr_b = prow_base + (16 * i + col) * 64;
            #pragma unroll
            for (int t4 = 0; t4 < 2; t4++) {
                float pr[4];
                #pragma unroll
                for (int r = 0; r < 4; r++) pr[r] = exp2f(st[t4][i][r]);
                uint2 pk;
                pk.x = pack_bf16_trunc(pr[0], pr[1]);
                pk.y = pack_bf16_trunc(pr[2], pr[3]);
                const int c2 = (2 * t4 + (quad >> 1)) ^ (col & 3);
                *(uint2*)(pr_b + 16 * c2 + 8 * (quad & 1)) = pk;
            }
        }

        // ---- O^T += V^T P^T ;  l += 1^T P^T  (K=32: one MFMA per pair) ----
        bfrag pf[2];
        #pragma unroll
        for (int i = 0; i < 2; i++)
            pf[i] = *(const bfrag*)
                (prow_base + (16 * i + col) * 64 + 16 * (quad ^ (col & 3)));
        #pragma unroll
        for (int d4 = 0; d4 < 4; d4++)
            #pragma unroll
            for (int i = 0; i < 2; i++)
                o[d4][i] = __builtin_amdgcn_mfma_f32_16x16x32_bf16(
                    vf[d4], pf[i], o[d4][i], 0, 0, 0);
        #pragma unroll
        for (int i = 0; i < 2; i++)
            ol[i] = __builtin_amdgcn_mfma_f32_16x16x32_bf16(
                ones, pf[i], ol[i], 0, 0, 0);
    }

    // ---- combine the two waves' partial O/l, normalize, write ----
    if (w == 1) {
        #pragma unroll
        for (int d4 = 0; d4 < 4; d4++)
            #pragma unroll
            for (int i = 0; i < 2; i++)
                #pragma unroll
                for (int r = 0; r < 4; r++)
                    comb[(d4 * 8 + i * 4 + r) * 64 + L] = o[d4][i][r];
        #pragma unroll
        for (int i = 0; i < 2; i++)
            comb[(32 + i) * 64 + L] = ol[i][0];
    }
    __syncthreads();
    if (w == 0) {
        #pragma unroll
        for (int i = 0; i < 2; i++) {
            const float l = ol[i][0] + comb[(32 + i) * 64 + L];
            const float inv = 1.0f / l;
            const int qg = q0 + 16 * i + col;
            #pragma unroll
            for (int d4 = 0; d4 < 4; d4++) {
                us4 pk;
                #pragma unroll
                for (int r = 0; r < 4; r++) {
                    const float val = o[d4][i][r] + comb[(d4 * 8 + i * 4 + r) * 64 + L];
                    pk[r] = f2bf(val * inv);
                }
                *(us4*)&ctxb[(size_t)qg * EMB + h * HD + 16 * d4 + 4 * quad] = pk;
            }
        }
    }
}

// ---------------------------------------------------------------------------
extern "C" void kernel_launch(void* const* d_in, const int* in_sizes, int n_in,
                              void* d_out, int out_size, void* d_ws, size_t ws_size,
                              hipStream_t stream) {
    const float* x      = (const float*)d_in[0];
    const float* wqkv_w = (const float*)d_in[2];
    const float* wqkv_b = (const float*)d_in[3];
    const float* out_w  = (const float*)d_in[4];
    const float* out_b  = (const float*)d_in[5];
    float* out = (float*)d_out;

    u16* qkvb = (u16*)d_ws;                        // [4096][3072] (V unused)
    u16* ctxb = qkvb + (size_t)S_LEN * E3;         // [4096][1024]
    u16* xb   = ctxb + (size_t)S_LEN * EMB;        // [4096][1024]
    u16* wt   = xb   + (size_t)S_LEN * EMB;        // [3072][1024]
    u16* owt  = wt   + (size_t)E3 * EMB;           // [1024][1024]
    u16* vtb  = owt  + (size_t)EMB * EMB;          // [16][64][4096]

    dim3 blk(256);

    cast_bf16_kernel<<<dim3(S_LEN * EMB / (256 * 8)), blk, 0, stream>>>(x, xb);
    transpose_cast_kernel<<<dim3(EMB / 64, E3 / 64), blk, 0, stream>>>(
        wqkv_w, wt, EMB, E3);
    transpose_cast_kernel<<<dim3(EMB / 64, EMB / 64), blk, 0, stream>>>(
        out_w, owt, EMB, EMB);

    // QKV projection + fused RoPE (+ q pre-scale) + fused V transpose
    gemm_bt_kernel<1, 4, 1, 3><<<dim3(S_LEN / 128, E3 / 128), blk, 0, stream>>>(
        xb, wt, wqkv_b, qkvb, vtb, S_LEN, E3, EMB);

    flash8_kernel<<<dim3(2048), dim3(128), 0, stream>>>(qkvb, vtb, ctxb);

    // output projection, 128x64 tiles -> 512 blocks (2/CU)
    gemm_bt_kernel<0, 2, 0, 2><<<dim3(S_LEN / 128, EMB / 64), blk, 0, stream>>>(
        ctxb, owt, out_b, out, nullptr, S_LEN, EMB, EMB);
}

// Round 10
// 256.284 us; speedup vs baseline: 1.1750x; 1.1750x over previous
//
#include <hip/hip_runtime.h>
#include <hip/hip_bf16.h>
#include <math.h>

#define S_LEN 4096
#define EMB   1024
#define E3    3072
#define NH    16
#define HD    64

typedef unsigned short u16;
typedef short          bfrag __attribute__((ext_vector_type(8)));  // 8 bf16
typedef float          ffrag __attribute__((ext_vector_type(4)));  // 4 f32
typedef unsigned short us8   __attribute__((ext_vector_type(8)));
typedef unsigned short us4   __attribute__((ext_vector_type(4)));

__device__ __forceinline__ u16 f2bf(float f) {
    union { float f; unsigned u; } v; v.f = f;
    unsigned r = v.u + 0x7fffu + ((v.u >> 16) & 1u);
    return (u16)(r >> 16);
}
__device__ __forceinline__ float bf2f(u16 b) {
    union { unsigned u; float f; } v; v.u = ((unsigned)b) << 16;
    return v.f;
}
// pack two f32 -> two bf16 (truncation) in one v_perm_b32
__device__ __forceinline__ unsigned pack_bf16_trunc(float lo, float hi) {
    union { float f; unsigned u; } a, b; a.f = lo; b.f = hi;
    return __builtin_amdgcn_perm(b.u, a.u, 0x07060302u);
}
// async global->LDS, 16B per lane; LDS dest = uniform base + lane*16
__device__ __forceinline__ void gld16(const void* g, void* l) {
    __builtin_amdgcn_global_load_lds(
        (const __attribute__((address_space(1))) unsigned int*)g,
        (__attribute__((address_space(3))) unsigned int*)l, 16, 0, 0);
}

// ---------------------------------------------------------------------------
// cast fp32 -> bf16, 8 elems/thread
// ---------------------------------------------------------------------------
__global__ __launch_bounds__(256)
void cast_bf16_kernel(const float* __restrict__ in, u16* __restrict__ out) {
    const size_t i = ((size_t)blockIdx.x * 256 + threadIdx.x) * 8;
    float4 a = *(const float4*)(in + i);
    float4 b = *(const float4*)(in + i + 4);
    us8 o;
    o[0]=f2bf(a.x); o[1]=f2bf(a.y); o[2]=f2bf(a.z); o[3]=f2bf(a.w);
    o[4]=f2bf(b.x); o[5]=f2bf(b.y); o[6]=f2bf(b.z); o[7]=f2bf(b.w);
    *(us8*)(out + i) = o;
}

// ---------------------------------------------------------------------------
// transpose+cast: in [R][C] fp32 -> out [C][R] bf16.  64x64 tiles.
// ---------------------------------------------------------------------------
__global__ __launch_bounds__(256)
void transpose_cast_kernel(const float* __restrict__ in, u16* __restrict__ out,
                           int R, int C) {
    __shared__ u16 T[64][72];
    const int r0 = blockIdx.x * 64, c0 = blockIdx.y * 64;
    const int t = threadIdx.x;
    const int rr = t >> 2, cc = (t & 3) * 16;

    const float* ip = in + (size_t)(r0 + rr) * C + c0 + cc;
    u16 tmp[16];
    #pragma unroll
    for (int i4 = 0; i4 < 4; i4++) {
        float4 v = ((const float4*)ip)[i4];
        tmp[4*i4+0]=f2bf(v.x); tmp[4*i4+1]=f2bf(v.y);
        tmp[4*i4+2]=f2bf(v.z); tmp[4*i4+3]=f2bf(v.w);
    }
    #pragma unroll
    for (int i8 = 0; i8 < 2; i8++) {
        us8 vv;
        #pragma unroll
        for (int j = 0; j < 8; j++) vv[j] = tmp[8*i8+j];
        *(us8*)&T[rr][cc + 8*i8] = vv;
    }
    __syncthreads();

    const int oc = t >> 2, orr = (t & 3) * 16;
    u16 ot[16];
    #pragma unroll
    for (int j = 0; j < 16; j++) ot[j] = T[orr + j][oc];
    u16* op = out + (size_t)(c0 + oc) * R + r0 + orr;
    #pragma unroll
    for (int i8 = 0; i8 < 2; i8++) {
        us8 vv;
        #pragma unroll
        for (int j = 0; j < 8; j++) vv[j] = ot[8*i8+j];
        *(us8*)(op + 8*i8) = vv;
    }
}

// ---------------------------------------------------------------------------
// bf16 MFMA GEMM, double-buffered: C[M,N] = A[M,K] * Bt[N,K]^T + bias
// Tile 128 x (32*NT); 4 waves as 2m x 2n; wave does 4x NT 16x16x32 tiles.
// ROPE=1 (requires NT=4):
//   n0 <  2048 : fuse RoPE rotation (+0.125*log2e scale for q) -> Cv (qkvb)
//   n0 >= 2048 : V region -- write bias-added values TRANSPOSED to vtp[d][s]
// ---------------------------------------------------------------------------
template <int OUT_BF16, int NT, int ROPE, int MINW>
__global__ __launch_bounds__(256, MINW)
void gemm_bt_kernel(const u16* __restrict__ A, const u16* __restrict__ Bt,
                    const float* __restrict__ bias, void* __restrict__ Cv,
                    u16* __restrict__ vtp, int M, int N, int K) {
    constexpr int BN = 32 * NT;       // block n-span
    constexpr int WS = 16 * NT;       // wave n-span
    __shared__ u16 As[2][128][32];
    __shared__ u16 Bs[2][BN][32];

    const int tid = threadIdx.x;
    const int w = tid >> 6, L = tid & 63;
    const int col = L & 15, quad = L >> 4;
    const int wm = w & 1, wn = w >> 1;
    const int m0 = blockIdx.x * 128, n0 = blockIdx.y * BN;

    ffrag acc[4][NT];
    #pragma unroll
    for (int a = 0; a < 4; a++)
        #pragma unroll
        for (int b = 0; b < NT; b++)
            #pragma unroll
            for (int r = 0; r < 4; r++) acc[a][b][r] = 0.f;

    const int srow = L >> 2;
    const int schk = L & 3;

    // prologue: stage k=0 into buf 0
    #pragma unroll
    for (int t = 0; t < 2; t++) {
        const int rg = (2 * w + t) * 16;
        gld16(A + (size_t)(m0 + rg + srow) * K + schk * 8, &As[0][rg][0]);
    }
    #pragma unroll
    for (int t = 0; t < NT / 2; t++) {
        const int rg = (w * (NT / 2) + t) * 16;
        gld16(Bt + (size_t)(n0 + rg + srow) * K + schk * 8, &Bs[0][rg][0]);
    }
    __syncthreads();

    int buf = 0;
    for (int k0 = 0; k0 < K; k0 += 32, buf ^= 1) {
        if (k0 + 32 < K) {
            #pragma unroll
            for (int t = 0; t < 2; t++) {
                const int rg = (2 * w + t) * 16;
                gld16(A + (size_t)(m0 + rg + srow) * K + k0 + 32 + schk * 8,
                      &As[buf ^ 1][rg][0]);
            }
            #pragma unroll
            for (int t = 0; t < NT / 2; t++) {
                const int rg = (w * (NT / 2) + t) * 16;
                gld16(Bt + (size_t)(n0 + rg + srow) * K + k0 + 32 + schk * 8,
                      &Bs[buf ^ 1][rg][0]);
            }
        }

        bfrag af[4], bf[NT];
        #pragma unroll
        for (int mt = 0; mt < 4; mt++)
            af[mt] = *(const bfrag*)&As[buf][64 * wm + 16 * mt + col][8 * quad];
        #pragma unroll
        for (int nt = 0; nt < NT; nt++)
            bf[nt] = *(const bfrag*)&Bs[buf][WS * wn + 16 * nt + col][8 * quad];
        #pragma unroll
        for (int mt = 0; mt < 4; mt++)
            #pragma unroll
            for (int nt = 0; nt < NT; nt++)
                acc[mt][nt] = __builtin_amdgcn_mfma_f32_16x16x32_bf16(
                    af[mt], bf[nt], acc[mt][nt], 0, 0, 0);

        __syncthreads();
    }

    float bv[NT];
    #pragma unroll
    for (int nt = 0; nt < NT; nt++) bv[nt] = bias[n0 + WS * wn + 16 * nt + col];

    if (ROPE && n0 < 2 * EMB) {
        // q (n<1024) or k (1024..2047): rotate (d, d+32) pairs.
        const float SCq = (n0 < EMB) ? 0.125f * 1.44269504088896f : 1.0f;
        const float C = 13.287712379549449f / 32.0f;   // log2(10000)/32
        float invf[2];
        invf[0] = exp2f(-(float)col * C);
        invf[1] = exp2f(-(float)(col + 16) * C);
        #pragma unroll
        for (int mt = 0; mt < 4; mt++) {
            #pragma unroll
            for (int r = 0; r < 4; r++) {
                const int mrow = m0 + 64 * wm + 16 * mt + 4 * quad + r;
                const float fs = (float)mrow;
                u16* cp = (u16*)Cv + (size_t)mrow * N + n0 + 64 * wn + col;
                #pragma unroll
                for (int pr = 0; pr < 2; pr++) {
                    float sn, cs;
                    sincosf(fs * invf[pr], &sn, &cs);
                    const float t1 = acc[mt][pr][r] + bv[pr];
                    const float t2 = acc[mt][pr + 2][r] + bv[pr + 2];
                    cp[16 * pr]      = f2bf((t1 * cs - t2 * sn) * SCq);
                    cp[16 * pr + 32] = f2bf((t2 * cs + t1 * sn) * SCq);
                }
            }
        }
    } else if (ROPE) {
        // V region: write transposed to vtp[d][s], d = n - 2048.
        #pragma unroll
        for (int nt = 0; nt < NT; nt++) {
            const int dg = n0 - 2 * EMB + WS * wn + 16 * nt + col;
            #pragma unroll
            for (int mt = 0; mt < 4; mt++) {
                const int s0 = m0 + 64 * wm + 16 * mt + 4 * quad;
                us4 pk;
                #pragma unroll
                for (int r = 0; r < 4; r++) pk[r] = f2bf(acc[mt][nt][r] + bv[nt]);
                *(us4*)&vtp[(size_t)dg * S_LEN + s0] = pk;
            }
        }
    } else {
        #pragma unroll
        for (int mt = 0; mt < 4; mt++) {
            #pragma unroll
            for (int r = 0; r < 4; r++) {
                const int m = m0 + 64 * wm + 16 * mt + 4 * quad + r;
                #pragma unroll
                for (int nt = 0; nt < NT; nt++) {
                    const int n = n0 + WS * wn + 16 * nt + col;
                    const float val = acc[mt][nt][r] + bv[nt];
                    if (OUT_BF16) ((u16*)Cv)[(size_t)m * N + n] = f2bf(val);
                    else          ((float*)Cv)[(size_t)m * N + n] = val;
                }
            }
        }
    }
}

// ---------------------------------------------------------------------------
// flash9: flash6 body + split-K load balancing.
// 128-q blocks, 4 waves x 32 q, dbuf K/V via global_load_lds (48 KB LDS,
// 3 blocks/CU).  Block types:
//   A (qi<16):            tiles [0, 2qi+2),  direct normalized write to ctxb
//   B (qi>=16, half 0):   tiles [0, qi+1),   no mask, partial write
//   C (qi>=16, half 1):   tiles [qi+1, 2qi+2), diagonal mask, partial write
// All block lengths in [2,32] tiles -> 768 blocks, ~3 resident/CU sustained
// (vs flash6's 1 long block/CU alone most of the time).  Partials: bf16 O
// (aliases dead xb, exactly 8.39 MB) + fp32 l (aliases dead wt); combine
// kernel sums halves and normalizes.  id&7 = XCD; 2 heads per XCD.
// Longest blocks issued first within each XCD lane.
// ---------------------------------------------------------------------------
__global__ __launch_bounds__(256, 3)
void flash9_kernel(const u16* __restrict__ qkvb, const u16* __restrict__ vt,
                   u16* __restrict__ ctxb, u16* __restrict__ pO,
                   float* __restrict__ pL) {
    __shared__ u16 QP[4][32][64];     // per-wave: Q rows, then P overlay
    __shared__ u16 Ks[2][64][64];
    __shared__ u16 Vs[2][64][64];

    const int id = blockIdx.x;                    // 0..767
    const int x  = id & 7;                        // XCD
    const int r  = id >> 3;                       // 0..95
    const int h  = x + 8 * (r >= 48);             // 2 heads per XCD
    const int rr = (r >= 48) ? (r - 48) : r;      // 0..47

    int type, qi, kt0, cnt;                       // 0=A,1=B,2=C
    if (rr < 16)      { type = 1; qi = 31 - rr;        kt0 = 0;      cnt = qi + 1; }
    else if (rr < 32) { type = 2; qi = 31 - (rr - 16); kt0 = qi + 1; cnt = qi + 1; }
    else              { type = 0; qi = 15 - (rr - 32); kt0 = 0;      cnt = 2 * qi + 2; }
    const int q0 = qi * 128;

    const int tid = threadIdx.x;
    const int w = tid >> 6, L = tid & 63;
    const int col = L & 15, quad = L >> 4;
    const int lr = L >> 3, lp = L & 7;
    const int lc = lp ^ lr;                       // swizzled chunk for staging

    const bool domask = (type != 1);
    const int nwt = cnt - ((domask && w < 2) ? 1 : 0);

    const size_t kArow = (size_t)(16 * w + lr) * E3 + EMB + h * HD + lc * 8;
    const size_t vArow = ((size_t)h * HD + 16 * w + lr) * S_LEN + lc * 8;
    const size_t kt0off  = (size_t)kt0 * 64 * E3;
    const size_t vt0off  = (size_t)kt0 * 64;

    // ---- stage Q (own wave's 32 rows) + K/V tile kt0 ----
    #pragma unroll
    for (int u = 0; u < 4; u++)
        gld16(qkvb + (size_t)(q0 + 32 * w + 8 * u + lr) * E3 + h * HD + lc * 8,
              &QP[w][8 * u][0]);
    #pragma unroll
    for (int u = 0; u < 2; u++) {
        gld16(qkvb + kArow + kt0off + (size_t)(8 * u) * E3,
              &Ks[0][16 * w + 8 * u][0]);
        gld16(vt + vArow + vt0off + (size_t)(8 * u) * S_LEN,
              &Vs[0][16 * w + 8 * u][0]);
    }
    __syncthreads();

    bfrag qf[2][2];
    #pragma unroll
    for (int i = 0; i < 2; i++)
        #pragma unroll
        for (int ks = 0; ks < 2; ks++)
            qf[i][ks] = *(const bfrag*)
                ((const char*)&QP[w][16 * i + col][0] +
                 16 * ((4 * ks + quad) ^ (col & 7)));

    bfrag ones;
    #pragma unroll
    for (int i = 0; i < 8; i++) ones[i] = (short)0x3F80;

    ffrag o[4][2], ol[2];
    #pragma unroll
    for (int d4 = 0; d4 < 4; d4++)
        #pragma unroll
        for (int i = 0; i < 2; i++)
            #pragma unroll
            for (int r2 = 0; r2 < 4; r2++) o[d4][i][r2] = 0.f;
    #pragma unroll
    for (int i = 0; i < 2; i++)
        #pragma unroll
        for (int r2 = 0; r2 < 4; r2++) ol[i][r2] = 0.f;

    #pragma unroll 1
    for (int t = 0; t < cnt; t++) {
        const int buf = t & 1;
        // prefetch next k-tile into the other buffer (before compute)
        if (t + 1 < cnt) {
            const size_t ko = kArow + kt0off + (size_t)(t + 1) * 64 * E3;
            const size_t vo = vArow + vt0off + (size_t)(t + 1) * 64;
            #pragma unroll
            for (int u = 0; u < 2; u++) {
                gld16(qkvb + ko + (size_t)(8 * u) * E3,
                      &Ks[buf ^ 1][16 * w + 8 * u][0]);
                gld16(vt + vo + (size_t)(8 * u) * S_LEN,
                      &Vs[buf ^ 1][16 * w + 8 * u][0]);
            }
        }

        if (t < nwt) {
            // ---- S^T = K Q^T ----
            ffrag st[4][2];
            #pragma unroll
            for (int t4 = 0; t4 < 4; t4++)
                #pragma unroll
                for (int i = 0; i < 2; i++)
                    #pragma unroll
                    for (int r2 = 0; r2 < 4; r2++) st[t4][i][r2] = 0.f;
            #pragma unroll
            for (int ks = 0; ks < 2; ks++) {
                bfrag kf[4];
                #pragma unroll
                for (int t4 = 0; t4 < 4; t4++)
                    kf[t4] = *(const bfrag*)
                        &Ks[buf][16 * t4 + col][(((4 * ks + quad) ^ (col & 7)) * 8)];
                #pragma unroll
                for (int t4 = 0; t4 < 4; t4++)
                    #pragma unroll
                    for (int i = 0; i < 2; i++)
                        st[t4][i] = __builtin_amdgcn_mfma_f32_16x16x32_bf16(
                            kf[t4], qf[i][ks], st[t4][i], 0, 0, 0);
            }

            // ---- causal mask: only this wave's diagonal tile ----
            if (domask && t == nwt - 1) {
                #pragma unroll
                for (int i = 0; i < 2; i++) {
                    const int qrel = 32 * (w & 1) + 16 * i + col;
                    #pragma unroll
                    for (int t4 = 0; t4 < 4; t4++) {
                        const int key0 = 16 * t4 + 4 * quad;
                        #pragma unroll
                        for (int r2 = 0; r2 < 4; r2++)
                            if (key0 + r2 > qrel) st[t4][i][r2] = -3.0e38f;
                    }
                }
            }

            // ---- softmax numerator: p = exp2(s), no shift ----
            #pragma unroll
            for (int i = 0; i < 2; i++) {
                const int prow = 16 * i + col;
                #pragma unroll
                for (int t4 = 0; t4 < 4; t4++) {
                    float pr[4];
                    #pragma unroll
                    for (int r2 = 0; r2 < 4; r2++) pr[r2] = exp2f(st[t4][i][r2]);
                    uint2 pk;
                    pk.x = pack_bf16_trunc(pr[0], pr[1]);
                    pk.y = pack_bf16_trunc(pr[2], pr[3]);
                    const int c2 = (2 * t4 + (quad >> 1)) ^ (col & 7);
                    *(uint2*)((char*)&QP[w][prow][0] + 16 * c2 + 8 * (quad & 1)) = pk;
                }
            }

            // ---- O^T += V^T P^T ;  l += 1^T P^T ----
            #pragma unroll
            for (int ks = 0; ks < 2; ks++) {
                bfrag vf[4];
                #pragma unroll
                for (int d4 = 0; d4 < 4; d4++)
                    vf[d4] = *(const bfrag*)
                        &Vs[buf][16 * d4 + col][(((4 * ks + quad) ^ (col & 7)) * 8)];
                bfrag pf[2];
                #pragma unroll
                for (int i = 0; i < 2; i++)
                    pf[i] = *(const bfrag*)
                        ((const char*)&QP[w][16 * i + col][0] +
                         16 * ((4 * ks + quad) ^ (col & 7)));
                #pragma unroll
                for (int d4 = 0; d4 < 4; d4++)
                    #pragma unroll
                    for (int i = 0; i < 2; i++)
                        o[d4][i] = __builtin_amdgcn_mfma_f32_16x16x32_bf16(
                            vf[d4], pf[i], o[d4][i], 0, 0, 0);
                #pragma unroll
                for (int i = 0; i < 2; i++)
                    ol[i] = __builtin_amdgcn_mfma_f32_16x16x32_bf16(
                        ones, pf[i], ol[i], 0, 0, 0);
            }
        }

        __syncthreads();   // compute done; next tile's loads drained here
    }

    // ---- epilogue ----
    if (type == 0) {
        // direct normalized write
        #pragma unroll
        for (int i = 0; i < 2; i++) {
            const float inv = 1.0f / ol[i][0];
            const int qg = q0 + 32 * w + 16 * i + col;
            #pragma unroll
            for (int d4 = 0; d4 < 4; d4++) {
                us4 pk;
                #pragma unroll
                for (int r2 = 0; r2 < 4; r2++) pk[r2] = f2bf(o[d4][i][r2] * inv);
                *(us4*)&ctxb[(size_t)qg * EMB + h * HD + 16 * d4 + 4 * quad] = pk;
            }
        }
    } else {
        // partial write: bf16 O + fp32 l
        const int half = type - 1;                 // B=0, C=1
        const int g = h * 16 + (qi - 16);
        u16* po = pO + (size_t)half * 256 * 128 * 64 + (size_t)g * 128 * 64;
        float* pl = pL + half * 256 * 128 + g * 128;
        #pragma unroll
        for (int i = 0; i < 2; i++) {
            const int qrow = 32 * w + 16 * i + col;
            #pragma unroll
            for (int d4 = 0; d4 < 4; d4++) {
                us4 pk;
                #pragma unroll
                for (int r2 = 0; r2 < 4; r2++) pk[r2] = f2bf(o[d4][i][r2]);
                *(us4*)&po[(size_t)qrow * 64 + 16 * d4 + 4 * quad] = pk;
            }
            if (quad == 0) pl[qrow] = ol[i][0];
        }
    }
}

// ---------------------------------------------------------------------------
// combine: out[q] = (O_a[q] + O_b[q]) / (l_a[q] + l_b[q]) for qi>=16 groups.
// ---------------------------------------------------------------------------
__global__ __launch_bounds__(256)
void combine_kernel(const u16* __restrict__ pO, const float* __restrict__ pL,
                    u16* __restrict__ ctxb) {
    const int g = blockIdx.x;                  // 0..255
    const int h = g >> 4, qi = 16 + (g & 15);
    const int t = threadIdx.x;
    const int q = t >> 1, dh = (t & 1) * 32;

    const float la = pL[g * 128 + q];
    const float lb = pL[256 * 128 + g * 128 + q];
    const float inv = 1.0f / (la + lb);

    const u16* a = pO + ((size_t)g * 128 + q) * 64 + dh;
    const u16* b = a + (size_t)256 * 128 * 64;
    u16* op = ctxb + (size_t)(qi * 128 + q) * EMB + h * HD + dh;

    #pragma unroll
    for (int j = 0; j < 4; j++) {
        us8 va = *(const us8*)(a + 8 * j);
        us8 vb = *(const us8*)(b + 8 * j);
        us8 vo;
        #pragma unroll
        for (int e = 0; e < 8; e++)
            vo[e] = f2bf((bf2f(va[e]) + bf2f(vb[e])) * inv);
        *(us8*)(op + 8 * j) = vo;
    }
}

// ---------------------------------------------------------------------------
extern "C" void kernel_launch(void* const* d_in, const int* in_sizes, int n_in,
                              void* d_out, int out_size, void* d_ws, size_t ws_size,
                              hipStream_t stream) {
    const float* x      = (const float*)d_in[0];
    const float* wqkv_w = (const float*)d_in[2];
    const float* wqkv_b = (const float*)d_in[3];
    const float* out_w  = (const float*)d_in[4];
    const float* out_b  = (const float*)d_in[5];
    float* out = (float*)d_out;

    u16* qkvb = (u16*)d_ws;                        // [4096][3072] (V unused)
    u16* ctxb = qkvb + (size_t)S_LEN * E3;         // [4096][1024]
    u16* xb   = ctxb + (size_t)S_LEN * EMB;        // [4096][1024]
    u16* wt   = xb   + (size_t)S_LEN * EMB;        // [3072][1024]
    u16* owt  = wt   + (size_t)E3 * EMB;           // [1024][1024]
    u16* vtb  = owt  + (size_t)EMB * EMB;          // [16][64][4096]

    // flash9 partial buffers alias regions dead after gemm1:
    u16*   pO = xb;            // 2 x 256 x 128 x 64 bf16 = 8.39 MB = |xb|
    float* pL = (float*)wt;    // 2 x 256 x 128 fp32 = 256 KB << |wt|

    dim3 blk(256);

    cast_bf16_kernel<<<dim3(S_LEN * EMB / (256 * 8)), blk, 0, stream>>>(x, xb);
    transpose_cast_kernel<<<dim3(EMB / 64, E3 / 64), blk, 0, stream>>>(
        wqkv_w, wt, EMB, E3);
    transpose_cast_kernel<<<dim3(EMB / 64, EMB / 64), blk, 0, stream>>>(
        out_w, owt, EMB, EMB);

    // QKV projection + fused RoPE (+ q pre-scale) + fused V transpose
    gemm_bt_kernel<1, 4, 1, 3><<<dim3(S_LEN / 128, E3 / 128), blk, 0, stream>>>(
        xb, wt, wqkv_b, qkvb, vtb, S_LEN, E3, EMB);

    flash9_kernel<<<dim3(768), blk, 0, stream>>>(qkvb, vtb, ctxb, pO, pL);
    combine_kernel<<<dim3(256), blk, 0, stream>>>(pO, pL, ctxb);

    // output projection, 128x64 tiles -> 512 blocks (2/CU)
    gemm_bt_kernel<0, 2, 0, 2><<<dim3(S_LEN / 128, EMB / 64), blk, 0, stream>>>(
        ctxb, owt, out_b, out, nullptr, S_LEN, EMB, EMB);
}